// Round 9
// baseline (315.456 us; speedup 1.0000x reference)
//
#include <hip/hip_runtime.h>
#include <hip/hip_bf16.h>

// CQAttention: B=16, Lc=1024, Lq=512, d=512.  f32 I/O, bf16 MFMA GEMMs, f32 acc.
// Round 9: (1) 64x64 wave tiles (4-wave/256-thread blocks) for G2/G4/G5 ->
// 0.5 KB LDS read per MFMA (was 0.75) — kernels are LDS-BW bound; (2) rowdots
// fused into k_mfma_S staging (kills 96 MB re-read kernel); (3) vectorized
// softstat/colwrite/transpose (float4 / v4bf).

#define NB 16
#define LC 1024
#define LQ 512
#define DM 512
#define D4 2048
#define NEGINF (-1e30f)
#define LDA64 72   // padded LDS k-stride for BK=64 tiles
#define LDA32 40   // padded LDS k-stride for BK=32 tiles

typedef __bf16 v8bf __attribute__((ext_vector_type(8)));
typedef __bf16 v4bf __attribute__((ext_vector_type(4)));
typedef float  v4f  __attribute__((ext_vector_type(4)));

#define MFMA16 __builtin_amdgcn_mfma_f32_16x16x32_bf16

// ---- 8-wave (512-thr) setup: wave (wm 0..1, wn 0..3) owns 64(m) x 32(n) ----
#define TILE_SETUP8 \
  const int t = threadIdx.x, lane = t & 63, wave = t >> 6; \
  const int wm = wave >> 2, wn = wave & 3, quad = lane >> 4, col = lane & 15;

#define ZERO_ACC8 \
  v4f acc[4][2]; \
  _Pragma("unroll") for (int x = 0; x < 4; ++x) \
  _Pragma("unroll") for (int y = 0; y < 2; ++y) \
  _Pragma("unroll") for (int r = 0; r < 4; ++r) acc[x][y][r] = 0.f;

#define FRAG_MMA8S(AL, BL, LDA, KO) do { \
  v8bf af_[4], bf_[2]; \
  _Pragma("unroll") for (int x = 0; x < 4; ++x) \
    af_[x] = *(const v8bf*)&AL[(wm * 64 + x * 16 + col) * LDA + KO + quad * 8]; \
  _Pragma("unroll") for (int y = 0; y < 2; ++y) \
    bf_[y] = *(const v8bf*)&BL[(wn * 32 + y * 16 + col) * LDA + KO + quad * 8]; \
  _Pragma("unroll") for (int x = 0; x < 4; ++x) \
  _Pragma("unroll") for (int y = 0; y < 2; ++y) \
    acc[x][y] = MFMA16(af_[x], bf_[y], acc[x][y], 0, 0, 0); \
} while (0)

// ---- 4-wave (256-thr) setup: wave (wm 0..1, wn 0..1) owns 64(m) x 64(n) ----
#define TILE_SETUP4 \
  const int t = threadIdx.x, lane = t & 63, wave = t >> 6; \
  const int wm = wave >> 1, wn = wave & 1, quad = lane >> 4, col = lane & 15;

#define ZERO_ACC4 \
  v4f acc[4][4]; \
  _Pragma("unroll") for (int x = 0; x < 4; ++x) \
  _Pragma("unroll") for (int y = 0; y < 4; ++y) \
  _Pragma("unroll") for (int r = 0; r < 4; ++r) acc[x][y][r] = 0.f;

#define FRAG_MMA4(AL, BL, LDA, KO) do { \
  v8bf af_[4], bf_[4]; \
  _Pragma("unroll") for (int x = 0; x < 4; ++x) \
    af_[x] = *(const v8bf*)&AL[(wm * 64 + x * 16 + col) * LDA + KO + quad * 8]; \
  _Pragma("unroll") for (int y = 0; y < 4; ++y) \
    bf_[y] = *(const v8bf*)&BL[(wn * 64 + y * 16 + col) * LDA + KO + quad * 8]; \
  _Pragma("unroll") for (int x = 0; x < 4; ++x) \
  _Pragma("unroll") for (int y = 0; y < 4; ++y) \
    acc[x][y] = MFMA16(af_[x], bf_[y], acc[x][y], 0, 0, 0); \
} while (0)

// XCD-aware remap (L2 locality for n-tile siblings sharing an A-tile).
__device__ __forceinline__ void xcd_remap(int& bx, int& by, int& bz) {
  const int gx = gridDim.x, gy = gridDim.y, gz = gridDim.z;
  int flat = bx + gx * (by + gy * bz);
  int per = (gx * gy * gz) >> 3;
  int nw = (flat & 7) * per + (flat >> 3);
  bx = nw % gx;
  int r = nw / gx;
  by = r % gy;
  bz = r / gy;
}

__device__ __forceinline__ v8bf cvt8f(float4 a, float4 b) {
  v8bf h;
  h[0] = (__bf16)a.x; h[1] = (__bf16)a.y; h[2] = (__bf16)a.z; h[3] = (__bf16)a.w;
  h[4] = (__bf16)b.x; h[5] = (__bf16)b.y; h[6] = (__bf16)b.z; h[7] = (__bf16)b.w;
  return h;
}

// ------- batched transpose: f32 in[R][Cd] -> bf16 outT[Cd][R] (vectorized) ----
__global__ void k_transpose(const float* __restrict__ in, __bf16* __restrict__ outT,
                            int R, int Cd) {
  __shared__ __bf16 tile[64][66];
  const int b = blockIdx.z;
  const int r0 = blockIdx.y * 64, c0 = blockIdx.x * 64;
  const float* inb = in + (size_t)b * R * Cd;
  __bf16* outb = outT + (size_t)b * Cd * R;
  const int rr = threadIdx.x >> 4, c4 = (threadIdx.x & 15) * 4;
#pragma unroll
  for (int p = 0; p < 4; ++p) {
    const int r = rr + p * 16;
    float4 f = *(const float4*)(inb + (size_t)(r0 + r) * Cd + c0 + c4);
    tile[r][c4 + 0] = (__bf16)f.x; tile[r][c4 + 1] = (__bf16)f.y;
    tile[r][c4 + 2] = (__bf16)f.z; tile[r][c4 + 3] = (__bf16)f.w;
  }
  __syncthreads();
  const int c = threadIdx.x & 63, rb = (threadIdx.x >> 6) * 4;
#pragma unroll
  for (int p = 0; p < 4; ++p) {
    const int r4 = rb + p * 16;
    v4bf h;
#pragma unroll
    for (int e = 0; e < 4; ++e) h[e] = tile[r4 + e][c];
    *(v4bf*)(outb + (size_t)(c0 + c) * R + r0 + r4) = h;
  }
}

// ------- OW f32 -> bf16 (once) -------
__global__ void k_owcvt(const float* __restrict__ OW, __bf16* __restrict__ OWb) {
  size_t i = ((size_t)blockIdx.x * 256 + threadIdx.x) * 4;
  float4 f = *(const float4*)(OW + i);
  v4bf h; h[0] = (__bf16)f.x; h[1] = (__bf16)f.y; h[2] = (__bf16)f.z; h[3] = (__bf16)f.w;
  *(v4bf*)(OWb + i) = h;
}

// ----- G1: S = cw1 + qw2 + (C*w3) @ Q^T  (BK=64, prefetch, FUSED rowdots) ----
__global__ __launch_bounds__(512) void k_mfma_S(
    const float* __restrict__ C, const float* __restrict__ Q, const float* __restrict__ w,
    float* __restrict__ S) {
  __shared__ __bf16 Al[128 * LDA64], Bl[128 * LDA64];
  __shared__ float cwL[128], qwL[128];
  int bx = blockIdx.x, by = blockIdx.y, bz = blockIdx.z;
  xcd_remap(bx, by, bz);
  const int b = bz, i0 = by * 128, j0 = bx * 128;
  TILE_SETUP8
  const int sr = t >> 2, skc = (t & 3) * 16;
  const float* Cb = C + (size_t)b * LC * DM;
  const float* Qb = Q + (size_t)b * LQ * DM;
  const float* w1 = w, *w2 = w + DM, *w3 = w + 2 * DM;
  float4 pc[4], pq[4];
  auto load = [&](int k0) {
    const float* ca = Cb + (size_t)(i0 + sr) * DM + k0 + skc;
    const float* qa = Qb + (size_t)(j0 + sr) * DM + k0 + skc;
#pragma unroll
    for (int u = 0; u < 4; ++u) {
      pc[u] = *(const float4*)(ca + 4 * u);
      pq[u] = *(const float4*)(qa + 4 * u);
    }
  };
  load(0);
  ZERO_ACC8
  float cdot = 0.f, qdot = 0.f;
  for (int k0 = 0; k0 < DM; k0 += 64) {
#pragma unroll
    for (int u = 0; u < 2; ++u) {
      float4 c0 = pc[2 * u], c1 = pc[2 * u + 1];
      float4 q0 = pq[2 * u], q1 = pq[2 * u + 1];
      const float* w3a = w3 + k0 + skc + 8 * u;
      float4 w30 = *(const float4*)w3a, w31 = *(const float4*)(w3a + 4);
      const float* w1a = w1 + k0 + skc + 8 * u;
      float4 w10 = *(const float4*)w1a, w11 = *(const float4*)(w1a + 4);
      const float* w2a = w2 + k0 + skc + 8 * u;
      float4 w20 = *(const float4*)w2a, w21 = *(const float4*)(w2a + 4);
      v8bf ah;
      ah[0] = (__bf16)(c0.x * w30.x); ah[1] = (__bf16)(c0.y * w30.y);
      ah[2] = (__bf16)(c0.z * w30.z); ah[3] = (__bf16)(c0.w * w30.w);
      ah[4] = (__bf16)(c1.x * w31.x); ah[5] = (__bf16)(c1.y * w31.y);
      ah[6] = (__bf16)(c1.z * w31.z); ah[7] = (__bf16)(c1.w * w31.w);
      *(v8bf*)&Al[sr * LDA64 + skc + 8 * u] = ah;
      *(v8bf*)&Bl[sr * LDA64 + skc + 8 * u] = cvt8f(q0, q1);
      cdot += c0.x * w10.x + c0.y * w10.y + c0.z * w10.z + c0.w * w10.w
            + c1.x * w11.x + c1.y * w11.y + c1.z * w11.z + c1.w * w11.w;
      qdot += q0.x * w20.x + q0.y * w20.y + q0.z * w20.z + q0.w * w20.w
            + q1.x * w21.x + q1.y * w21.y + q1.z * w21.z + q1.w * w21.w;
    }
    __syncthreads();
    int kn = k0 + 64; if (kn >= DM) kn = 0;
    load(kn);
    FRAG_MMA8S(Al, Bl, LDA64, 0);
    FRAG_MMA8S(Al, Bl, LDA64, 32);
    __syncthreads();
  }
  // reduce dots across the 4 threads sharing row sr (consecutive lanes)
  cdot += __shfl_xor(cdot, 1); cdot += __shfl_xor(cdot, 2);
  qdot += __shfl_xor(qdot, 1); qdot += __shfl_xor(qdot, 2);
  if ((t & 3) == 0) { cwL[sr] = cdot; qwL[sr] = qdot; }
  __syncthreads();
  float* Sb = S + (size_t)b * LC * LQ;
#pragma unroll
  for (int x = 0; x < 4; ++x) {
    const int ml = wm * 64 + x * 16 + quad * 4;
    float cv[4];
#pragma unroll
    for (int r = 0; r < 4; ++r) cv[r] = cwL[ml + r];
#pragma unroll
    for (int y = 0; y < 2; ++y) {
      const int jl = wn * 32 + y * 16 + col;
      const float qv = qwL[jl];
#pragma unroll
      for (int r = 0; r < 4; ++r)
        Sb[(size_t)(i0 + ml + r) * LQ + j0 + jl] = acc[x][y][r] + cv[r] + qv;
    }
  }
}

// ---- fused: row softmax (qmask) -> S1  AND per-64i-chunk column stats ----
__global__ __launch_bounds__(1024) void k_softstat(
    const float* __restrict__ S, const float* __restrict__ qmask,
    const float* __restrict__ cmask, __bf16* __restrict__ S1,
    float2* __restrict__ pstat) {
  __shared__ float2 cst[16][LQ];
  const int b = blockIdx.y, ic = blockIdx.x;
  const int tid = threadIdx.x, wv = tid >> 6, lane = tid & 63;
  const int jb = lane * 8;
  const float* qm  = qmask + b * LQ;
  const float* cm  = cmask + b * LC + ic * 64;
  const float* Sb  = S  + ((size_t)b * LC + ic * 64) * LQ;
  __bf16*      S1b = S1 + ((size_t)b * LC + ic * 64) * LQ;
  float qv[8];
  {
    float4 q0 = *(const float4*)(qm + jb), q1 = *(const float4*)(qm + jb + 4);
    qv[0] = q0.x; qv[1] = q0.y; qv[2] = q0.z; qv[3] = q0.w;
    qv[4] = q1.x; qv[5] = q1.y; qv[6] = q1.z; qv[7] = q1.w;
  }
  float colm[8], cols[8];
#pragma unroll
  for (int e = 0; e < 8; ++e) { colm[e] = -3e38f; cols[e] = 0.f; }
  for (int it = 0; it < 4; ++it) {
    const int r = wv * 4 + it;
    const float cmv = cm[r];
    const float* Srow = Sb + (size_t)r * LQ + jb;
    float4 s0 = *(const float4*)Srow, s1 = *(const float4*)(Srow + 4);
    float sv[8] = {s0.x, s0.y, s0.z, s0.w, s1.x, s1.y, s1.z, s1.w};
    float l1[8];
    float m = -3e38f;
#pragma unroll
    for (int e = 0; e < 8; ++e) {
      l1[e] = qv[e] * sv[e] + (1.f - qv[e]) * NEGINF;
      m = fmaxf(m, l1[e]);
    }
#pragma unroll
    for (int off = 32; off; off >>= 1) m = fmaxf(m, __shfl_xor(m, off, 64));
    float ex[8], s = 0.f;
#pragma unroll
    for (int e = 0; e < 8; ++e) { ex[e] = __expf(l1[e] - m); s += ex[e]; }
#pragma unroll
    for (int off = 32; off; off >>= 1) s += __shfl_xor(s, off, 64);
    const float inv = 1.f / s;
    v8bf h;
#pragma unroll
    for (int e = 0; e < 8; ++e) h[e] = (__bf16)(ex[e] * inv);
    *(v8bf*)(S1b + (size_t)r * LQ + jb) = h;
#pragma unroll
    for (int e = 0; e < 8; ++e) {
      float l2 = cmv * sv[e] + (1.f - cmv) * NEGINF;
      if (l2 > colm[e]) { cols[e] *= __expf(colm[e] - l2); colm[e] = l2; }
      cols[e] += __expf(l2 - colm[e]);
    }
  }
#pragma unroll
  for (int e = 0; e < 8; ++e) cst[wv][jb + e] = make_float2(colm[e], cols[e]);
  __syncthreads();
  if (tid < LQ) {
    float M = -3e38f, Sd = 0.f;
#pragma unroll
    for (int k = 0; k < 16; ++k) {
      float2 p = cst[k][tid];
      float nM = fmaxf(M, p.x);
      Sd = Sd * __expf(M - nM) + p.y * __expf(p.x - nM);
      M = nM;
    }
    pstat[((size_t)(b * 16 + ic) * LQ) + tid] = make_float2(M, Sd);
  }
}

// ---- col softmax phase 2: combine stats, write TRANSPOSED S2T[j][i] ----
__global__ void k_colwrite(const float* __restrict__ S, const float* __restrict__ cmask,
                           const float2* __restrict__ pstat, __bf16* __restrict__ S2T) {
  __shared__ float Mf[64], If[64];
  __shared__ __bf16 tile[64][66];
  const int b = blockIdx.z, ic = blockIdx.y, j0 = blockIdx.x * 64;
  if (threadIdx.x < 64) {
    float M = -3e38f, Sd = 0.f;
#pragma unroll
    for (int k = 0; k < 16; ++k) {
      float2 p = pstat[((size_t)(b * 16 + k) * LQ) + j0 + threadIdx.x];
      float nM = fmaxf(M, p.x);
      Sd = Sd * __expf(M - nM) + p.y * __expf(p.x - nM);
      M = nM;
    }
    Mf[threadIdx.x] = M; If[threadIdx.x] = 1.f / Sd;
  }
  __syncthreads();
  const float* Sb = S + ((size_t)b * LC + ic * 64) * LQ;
  const float* cm = cmask + b * LC + ic * 64;
  const int rr = threadIdx.x >> 4, c4 = (threadIdx.x & 15) * 4;
#pragma unroll
  for (int p = 0; p < 4; ++p) {
    const int r = rr + p * 16;
    const float mk = cm[r];
    float4 sv = *(const float4*)(Sb + (size_t)r * LQ + j0 + c4);
    float s[4] = {sv.x, sv.y, sv.z, sv.w};
#pragma unroll
    for (int e = 0; e < 4; ++e) {
      float logit = mk * s[e] + (1.f - mk) * NEGINF;
      tile[r][c4 + e] = (__bf16)(__expf(logit - Mf[c4 + e]) * If[c4 + e]);
    }
  }
  __syncthreads();
  __bf16* S2Tb = S2T + ((size_t)b * LQ + j0) * LC + ic * 64;
  const int c = threadIdx.x & 63, rb = (threadIdx.x >> 6) * 4;
#pragma unroll
  for (int p = 0; p < 4; ++p) {
    const int r4 = rb + p * 16;
    v4bf h;
#pragma unroll
    for (int e = 0; e < 4; ++e) h[e] = tile[r4 + e][c];
    *(v4bf*)(S2Tb + (size_t)c * LC + r4) = h;
  }
}

// ---------------- G2: A = S1 @ Q  (4-wave 64x64, BK=64, prefetch) -----------
__global__ __launch_bounds__(256) void k_mfma_A(
    const __bf16* __restrict__ S1, const __bf16* __restrict__ QT, __bf16* __restrict__ Aw) {
  __shared__ __bf16 Al[128 * LDA64], Bl[128 * LDA64];
  int bx = blockIdx.x, by = blockIdx.y, bz = blockIdx.z;
  xcd_remap(bx, by, bz);
  const int b = bz, i0 = by * 128, n0 = bx * 128;
  TILE_SETUP4
  const int sr = t >> 1, kh = (t & 1) * 32;
  const __bf16* Ar = S1 + (size_t)b * LC * LQ + (size_t)(i0 + sr) * LQ + kh;
  const __bf16* Br = QT + (size_t)b * DM * LQ + (size_t)(n0 + sr) * LQ + kh;
  v8bf pa[4], pb[4];
  auto load = [&](int k0) {
#pragma unroll
    for (int u = 0; u < 4; ++u) {
      pa[u] = *(const v8bf*)(Ar + k0 + 8 * u);
      pb[u] = *(const v8bf*)(Br + k0 + 8 * u);
    }
  };
  load(0);
  ZERO_ACC4
  for (int k0 = 0; k0 < LQ; k0 += 64) {
#pragma unroll
    for (int u = 0; u < 4; ++u) {
      *(v8bf*)&Al[sr * LDA64 + kh + 8 * u] = pa[u];
      *(v8bf*)&Bl[sr * LDA64 + kh + 8 * u] = pb[u];
    }
    __syncthreads();
    int kn = k0 + 64; if (kn >= LQ) kn = 0;
    load(kn);
    FRAG_MMA4(Al, Bl, LDA64, 0);
    FRAG_MMA4(Al, Bl, LDA64, 32);
    __syncthreads();
  }
  __bf16* Ab = Aw + (size_t)b * LC * DM;
#pragma unroll
  for (int x = 0; x < 4; ++x) {
    const int mB = i0 + wm * 64 + x * 16 + quad * 4;
#pragma unroll
    for (int y = 0; y < 4; ++y) {
      const int n = n0 + wn * 64 + y * 16 + col;
#pragma unroll
      for (int r = 0; r < 4; ++r)
        Ab[(size_t)(mB + r) * DM + n] = (__bf16)acc[x][y][r];
    }
  }
}

// ------- G3: S2TC^T[n][j]  (8-wave, K=Lc, BK=64, prefetch) ----
__global__ __launch_bounds__(512) void k_mfma_T(
    const __bf16* __restrict__ S2T, const __bf16* __restrict__ CT, __bf16* __restrict__ S2TCT) {
  __shared__ __bf16 Al[128 * LDA64], Bl[128 * LDA64];
  int bx = blockIdx.x, by = blockIdx.y, bz = blockIdx.z;
  xcd_remap(bx, by, bz);
  const int b = bz, j0 = by * 128, n0 = bx * 128;
  TILE_SETUP8
  const int sr = t >> 2, skc = (t & 3) * 16;
  const __bf16* Ar = S2T + (size_t)b * LQ * LC + (size_t)(j0 + sr) * LC + skc;
  const __bf16* Br = CT  + (size_t)b * DM * LC + (size_t)(n0 + sr) * LC + skc;
  v8bf pa0, pa1, pb0, pb1;
  auto load = [&](int k0) {
    pa0 = *(const v8bf*)(Ar + k0); pa1 = *(const v8bf*)(Ar + k0 + 8);
    pb0 = *(const v8bf*)(Br + k0); pb1 = *(const v8bf*)(Br + k0 + 8);
  };
  load(0);
  ZERO_ACC8
  for (int k0 = 0; k0 < LC; k0 += 64) {
    *(v8bf*)&Al[sr * LDA64 + skc] = pa0; *(v8bf*)&Al[sr * LDA64 + skc + 8] = pa1;
    *(v8bf*)&Bl[sr * LDA64 + skc] = pb0; *(v8bf*)&Bl[sr * LDA64 + skc + 8] = pb1;
    __syncthreads();
    int kn = k0 + 64; if (kn >= LC) kn = 0;
    load(kn);
    FRAG_MMA8S(Al, Bl, LDA64, 0);
    FRAG_MMA8S(Al, Bl, LDA64, 32);
    __syncthreads();
  }
#pragma unroll
  for (int x = 0; x < 4; ++x) {
    const int jB = j0 + wm * 64 + x * 16 + quad * 4;
#pragma unroll
    for (int y = 0; y < 2; ++y) {
      const int n = n0 + wn * 32 + y * 16 + col;
      v4bf h;
#pragma unroll
      for (int r = 0; r < 4; ++r) h[r] = (__bf16)acc[x][y][r];
      *(v4bf*)&S2TCT[((size_t)b * DM + n) * LQ + jB] = h;
    }
  }
}

// ---------------- G4: Bm = S1 @ S2TC  (4-wave 64x64, BK=64) ----------------
__global__ __launch_bounds__(256) void k_mfma_Bm(
    const __bf16* __restrict__ S1, const __bf16* __restrict__ S2TCT, __bf16* __restrict__ Bmw) {
  __shared__ __bf16 Al[128 * LDA64], Bl[128 * LDA64];
  int bx = blockIdx.x, by = blockIdx.y, bz = blockIdx.z;
  xcd_remap(bx, by, bz);
  const int b = bz, i0 = by * 128, n0 = bx * 128;
  TILE_SETUP4
  const int sr = t >> 1, kh = (t & 1) * 32;
  const __bf16* Ar = S1    + (size_t)b * LC * LQ + (size_t)(i0 + sr) * LQ + kh;
  const __bf16* Br = S2TCT + (size_t)b * DM * LQ + (size_t)(n0 + sr) * LQ + kh;
  v8bf pa[4], pb[4];
  auto load = [&](int k0) {
#pragma unroll
    for (int u = 0; u < 4; ++u) {
      pa[u] = *(const v8bf*)(Ar + k0 + 8 * u);
      pb[u] = *(const v8bf*)(Br + k0 + 8 * u);
    }
  };
  load(0);
  ZERO_ACC4
  for (int k0 = 0; k0 < LQ; k0 += 64) {
#pragma unroll
    for (int u = 0; u < 4; ++u) {
      *(v8bf*)&Al[sr * LDA64 + kh + 8 * u] = pa[u];
      *(v8bf*)&Bl[sr * LDA64 + kh + 8 * u] = pb[u];
    }
    __syncthreads();
    int kn = k0 + 64; if (kn >= LQ) kn = 0;
    load(kn);
    FRAG_MMA4(Al, Bl, LDA64, 0);
    FRAG_MMA4(Al, Bl, LDA64, 32);
    __syncthreads();
  }
  __bf16* Bb = Bmw + (size_t)b * LC * DM;
#pragma unroll
  for (int x = 0; x < 4; ++x) {
    const int mB = i0 + wm * 64 + x * 16 + quad * 4;
#pragma unroll
    for (int y = 0; y < 4; ++y) {
      const int n = n0 + wn * 64 + y * 16 + col;
#pragma unroll
      for (int r = 0; r < 4; ++r)
        Bb[(size_t)(mB + r) * DM + n] = (__bf16)acc[x][y][r];
    }
  }
}

// ---- G5: out = [C, A, C*A, C*Bm] @ out_w^T + out_b (4-wave 64x64, 4-seg) ----
__global__ __launch_bounds__(256) void k_mfma_out(
    const float* __restrict__ C, const __bf16* __restrict__ Aw, const __bf16* __restrict__ Bmw,
    const __bf16* __restrict__ OWb, const float* __restrict__ ob, float* __restrict__ out) {
  __shared__ __bf16 Asg[4][128 * LDA32], Bsg[4][128 * LDA32];   // 80 KiB
  int bx = blockIdx.x, by = blockIdx.y, bz = blockIdx.z;
  xcd_remap(bx, by, bz);
  const int b = bz, i0 = by * 128, n0 = bx * 128;
  TILE_SETUP4
  const int sr = t >> 1, kh = (t & 1) * 16;
  const float*  Cr = C   + (size_t)b * LC * DM + (size_t)(i0 + sr) * DM + kh;
  const __bf16* Ar = Aw  + (size_t)b * LC * DM + (size_t)(i0 + sr) * DM + kh;
  const __bf16* Br = Bmw + (size_t)b * LC * DM + (size_t)(i0 + sr) * DM + kh;
  const __bf16* Wr = OWb + (size_t)(n0 + sr) * D4 + kh;
  float4 pc[4]; v8bf pA[2], pB[2], pw[4][2];
  auto load = [&](int kl) {
#pragma unroll
    for (int u = 0; u < 4; ++u) pc[u] = *(const float4*)(Cr + kl + 4 * u);
#pragma unroll
    for (int u = 0; u < 2; ++u) {
      pA[u] = *(const v8bf*)(Ar + kl + 8 * u);
      pB[u] = *(const v8bf*)(Br + kl + 8 * u);
    }
#pragma unroll
    for (int s = 0; s < 4; ++s)
#pragma unroll
      for (int u = 0; u < 2; ++u) pw[s][u] = *(const v8bf*)(Wr + s * DM + kl + 8 * u);
  };
  load(0);
  ZERO_ACC4
  for (int kl = 0; kl < DM; kl += 32) {
#pragma unroll
    for (int u = 0; u < 2; ++u) {
      float4 f0 = pc[2 * u], f1 = pc[2 * u + 1];
      float cf[8] = {f0.x, f0.y, f0.z, f0.w, f1.x, f1.y, f1.z, f1.w};
      v8bf hC, hCA, hCB;
#pragma unroll
      for (int e = 0; e < 8; ++e) {
        hC[e]  = (__bf16)cf[e];
        hCA[e] = (__bf16)(cf[e] * (float)pA[u][e]);
        hCB[e] = (__bf16)(cf[e] * (float)pB[u][e]);
      }
      const int off = sr * LDA32 + kh + 8 * u;
      *(v8bf*)&Asg[0][off] = hC;
      *(v8bf*)&Asg[1][off] = pA[u];
      *(v8bf*)&Asg[2][off] = hCA;
      *(v8bf*)&Asg[3][off] = hCB;
#pragma unroll
      for (int s = 0; s < 4; ++s) *(v8bf*)&Bsg[s][off] = pw[s][u];
    }
    __syncthreads();
    int kn = kl + 32; if (kn >= DM) kn = 0;
    load(kn);
#pragma unroll
    for (int s = 0; s < 4; ++s) FRAG_MMA4(Asg[s], Bsg[s], LDA32, 0);
    __syncthreads();
  }
  float* outb = out + (size_t)b * LC * DM;
#pragma unroll
  for (int x = 0; x < 4; ++x) {
    const int mB = i0 + wm * 64 + x * 16 + quad * 4;
#pragma unroll
    for (int y = 0; y < 4; ++y) {
      const int n = n0 + wn * 64 + y * 16 + col;
      const float bv = ob[n];
#pragma unroll
      for (int r = 0; r < 4; ++r)
        outb[(size_t)(mB + r) * DM + n] = acc[x][y][r] + bv;
    }
  }
}

extern "C" void kernel_launch(void* const* d_in, const int* in_sizes, int n_in,
                              void* d_out, int out_size, void* d_ws, size_t ws_size,
                              hipStream_t stream) {
  const float* C     = (const float*)d_in[0];
  const float* Q     = (const float*)d_in[1];
  const float* cmask = (const float*)d_in[2];
  const float* qmask = (const float*)d_in[3];
  const float* w     = (const float*)d_in[4];
  const float* out_w = (const float*)d_in[5];
  const float* out_b = (const float*)d_in[6];
  float* out = (float*)d_out;

  // ---- workspace carve (72 MiB + 128 KiB; validated). Aliased by lifetime:
  //  R[0,16Mi):   S.lo          -> Aw
  //  R[16,32Mi):  S.hi          -> CT -> Bmw
  //  +32Mi: S1 (16 Mi)
  //  +48Mi: S2T (16 Mi)        -> OWbf (2 Mi, after k_mfma_T)
  //  +64Mi: pstat(1Mi) -> QT(8Mi) -> S2TCT(8Mi)
  char* base = (char*)d_ws;
  char*   R     = base + 131072;
  float*  S     = (float*)R;
  __bf16* Aw    = (__bf16*)R;
  __bf16* CT    = (__bf16*)(R + (16u << 20));
  __bf16* Bmw   = (__bf16*)(R + (16u << 20));
  __bf16* S1    = (__bf16*)(base + 131072 + (32u << 20));
  __bf16* S2T   = (__bf16*)(base + 131072 + (48u << 20));
  __bf16* OWbf  = S2T;   // 2 MiB, written after k_mfma_T consumes S2T
  char*   Z     = base + 131072 + (64u << 20);
  float2* pstat = (float2*)Z;
  __bf16* QT    = (__bf16*)Z;
  __bf16* S2TCT = (__bf16*)Z;
  (void)in_sizes; (void)n_in; (void)out_size; (void)ws_size;

  k_mfma_S<<<dim3(LQ / 128, LC / 128, NB), 512, 0, stream>>>(C, Q, w, S);
  k_softstat<<<dim3(LC / 64, NB), 1024, 0, stream>>>(S, qmask, cmask, S1, pstat);
  k_colwrite<<<dim3(LQ / 64, LC / 64, NB), 256, 0, stream>>>(S, cmask, pstat, S2T);
  k_transpose<<<dim3(DM / 64, LQ / 64, NB), 256, 0, stream>>>(Q, QT, LQ, DM);
  k_transpose<<<dim3(DM / 64, LC / 64, NB), 256, 0, stream>>>(C, CT, LC, DM);
  k_mfma_A<<<dim3(DM / 128, LC / 128, NB), 256, 0, stream>>>(S1, QT, Aw);
  k_mfma_T<<<dim3(DM / 128, LQ / 128, NB), 512, 0, stream>>>(S2T, CT, S2TCT);
  k_owcvt<<<DM * D4 / 1024, 256, 0, stream>>>(out_w, OWbf);
  k_mfma_Bm<<<dim3(DM / 128, LC / 128, NB), 256, 0, stream>>>(S1, S2TCT, Bmw);
  k_mfma_out<<<dim3(DM / 128, LC / 128, NB), 256, 0, stream>>>(C, Aw, Bmw, OWbf, out_b, out);
}

// Round 10
// 284.318 us; speedup vs baseline: 1.1095x; 1.1095x over previous
//
#include <hip/hip_runtime.h>
#include <hip/hip_bf16.h>

// CQAttention: B=16, Lc=1024, Lq=512, d=512.  f32 I/O, bf16 MFMA GEMMs, f32 acc.
// Round 10: revert MFMA GEMMs to R8 8-wave/64x32 shapes (R9's 4-wave/64x64
// traded occupancy for LDS locality at net loss). New: (1) G5 B-operand moved
// out of LDS — k_owfrag pre-permutes out_w into MFMA fragment order so each
// wave's B-frag is one coalesced 1KB global load (L2-resident, 2MB);
// LDS 80->40 KB. (2) colwrite/transpose writes re-tiled to 32B/thread
// contiguous (were 8B at 2KB stride). Keep fused rowdots + vectorized aux.

#define NB 16
#define LC 1024
#define LQ 512
#define DM 512
#define D4 2048
#define NEGINF (-1e30f)
#define LDA64 72   // padded LDS k-stride for BK=64 tiles (bf16 elems)
#define LDA32 40   // padded LDS k-stride for BK=32 tiles

typedef __bf16 v8bf __attribute__((ext_vector_type(8)));
typedef __bf16 v4bf __attribute__((ext_vector_type(4)));
typedef float  v4f  __attribute__((ext_vector_type(4)));

#define MFMA16 __builtin_amdgcn_mfma_f32_16x16x32_bf16

// ---- 8-wave (512-thr) setup: wave (wm 0..1, wn 0..3) owns 64(m) x 32(n) ----
#define TILE_SETUP8 \
  const int t = threadIdx.x, lane = t & 63, wave = t >> 6; \
  const int wm = wave >> 2, wn = wave & 3, quad = lane >> 4, col = lane & 15;

#define ZERO_ACC8 \
  v4f acc[4][2]; \
  _Pragma("unroll") for (int x = 0; x < 4; ++x) \
  _Pragma("unroll") for (int y = 0; y < 2; ++y) \
  _Pragma("unroll") for (int r = 0; r < 4; ++r) acc[x][y][r] = 0.f;

#define FRAG_MMA8S(AL, BL, LDA, KO) do { \
  v8bf af_[4], bf_[2]; \
  _Pragma("unroll") for (int x = 0; x < 4; ++x) \
    af_[x] = *(const v8bf*)&AL[(wm * 64 + x * 16 + col) * LDA + KO + quad * 8]; \
  _Pragma("unroll") for (int y = 0; y < 2; ++y) \
    bf_[y] = *(const v8bf*)&BL[(wn * 32 + y * 16 + col) * LDA + KO + quad * 8]; \
  _Pragma("unroll") for (int x = 0; x < 4; ++x) \
  _Pragma("unroll") for (int y = 0; y < 2; ++y) \
    acc[x][y] = MFMA16(af_[x], bf_[y], acc[x][y], 0, 0, 0); \
} while (0)

// XCD-aware remap (L2 locality for n-tile siblings sharing an A-tile).
__device__ __forceinline__ void xcd_remap(int& bx, int& by, int& bz) {
  const int gx = gridDim.x, gy = gridDim.y, gz = gridDim.z;
  int flat = bx + gx * (by + gy * bz);
  int per = (gx * gy * gz) >> 3;
  int nw = (flat & 7) * per + (flat >> 3);
  bx = nw % gx;
  int r = nw / gx;
  by = r % gy;
  bz = r / gy;
}

__device__ __forceinline__ v8bf cvt8f(float4 a, float4 b) {
  v8bf h;
  h[0] = (__bf16)a.x; h[1] = (__bf16)a.y; h[2] = (__bf16)a.z; h[3] = (__bf16)a.w;
  h[4] = (__bf16)b.x; h[5] = (__bf16)b.y; h[6] = (__bf16)b.z; h[7] = (__bf16)b.w;
  return h;
}

// ------- batched transpose: f32 in[R][Cd] -> bf16 outT[Cd][R] -------
__global__ void k_transpose(const float* __restrict__ in, __bf16* __restrict__ outT,
                            int R, int Cd) {
  __shared__ __bf16 tile[64][66];
  const int b = blockIdx.z;
  const int r0 = blockIdx.y * 64, c0 = blockIdx.x * 64;
  const float* inb = in + (size_t)b * R * Cd;
  __bf16* outb = outT + (size_t)b * Cd * R;
  const int rr = threadIdx.x >> 4, c4 = (threadIdx.x & 15) * 4;
#pragma unroll
  for (int p = 0; p < 4; ++p) {
    const int r = rr + p * 16;
    float4 f = *(const float4*)(inb + (size_t)(r0 + r) * Cd + c0 + c4);
    tile[r][c4 + 0] = (__bf16)f.x; tile[r][c4 + 1] = (__bf16)f.y;
    tile[r][c4 + 2] = (__bf16)f.z; tile[r][c4 + 3] = (__bf16)f.w;
  }
  __syncthreads();
  // write: thread -> out row cc, 16 consecutive r (32B contiguous x2)
  const int cc = threadIdx.x >> 2, r16 = (threadIdx.x & 3) * 16;
  v8bf h0, h1;
#pragma unroll
  for (int e = 0; e < 8; ++e) { h0[e] = tile[r16 + e][cc]; h1[e] = tile[r16 + 8 + e][cc]; }
  *(v8bf*)(outb + (size_t)(c0 + cc) * R + r0 + r16) = h0;
  *(v8bf*)(outb + (size_t)(c0 + cc) * R + r0 + r16 + 8) = h1;
}

// ------- out_w f32 -> bf16 in MFMA B-fragment order -------
// frag f = nt*64 + kc  (nt = n>>4, kc = k>>5); within frag: lane*8 elems,
// element (lane,e) = OW[nt*16 + (lane&15)][kc*32 + (lane>>4)*8 + e].
__global__ void k_owfrag(const float* __restrict__ OW, __bf16* __restrict__ Wf) {
  const int gid = blockIdx.x * 256 + threadIdx.x;   // 2048 frags * 64 lanes
  const int lane = gid & 63, f = gid >> 6;
  const int nt = f >> 6, kc = f & 63;
  const int n = nt * 16 + (lane & 15);
  const int k = kc * 32 + (lane >> 4) * 8;
  const float* src = OW + (size_t)n * D4 + k;
  float4 a = *(const float4*)src, b = *(const float4*)(src + 4);
  *(v8bf*)(Wf + (size_t)f * 512 + lane * 8) = cvt8f(a, b);
}

// ----- G1: S = cw1 + qw2 + (C*w3) @ Q^T  (BK=64, prefetch, FUSED rowdots) ----
__global__ __launch_bounds__(512) void k_mfma_S(
    const float* __restrict__ C, const float* __restrict__ Q, const float* __restrict__ w,
    float* __restrict__ S) {
  __shared__ __bf16 Al[128 * LDA64], Bl[128 * LDA64];
  __shared__ float cwL[128], qwL[128];
  int bx = blockIdx.x, by = blockIdx.y, bz = blockIdx.z;
  xcd_remap(bx, by, bz);
  const int b = bz, i0 = by * 128, j0 = bx * 128;
  TILE_SETUP8
  const int sr = t >> 2, skc = (t & 3) * 16;
  const float* Cb = C + (size_t)b * LC * DM;
  const float* Qb = Q + (size_t)b * LQ * DM;
  const float* w1 = w, *w2 = w + DM, *w3 = w + 2 * DM;
  float4 pc[4], pq[4];
  auto load = [&](int k0) {
    const float* ca = Cb + (size_t)(i0 + sr) * DM + k0 + skc;
    const float* qa = Qb + (size_t)(j0 + sr) * DM + k0 + skc;
#pragma unroll
    for (int u = 0; u < 4; ++u) {
      pc[u] = *(const float4*)(ca + 4 * u);
      pq[u] = *(const float4*)(qa + 4 * u);
    }
  };
  load(0);
  ZERO_ACC8
  float cdot = 0.f, qdot = 0.f;
  for (int k0 = 0; k0 < DM; k0 += 64) {
#pragma unroll
    for (int u = 0; u < 2; ++u) {
      float4 c0 = pc[2 * u], c1 = pc[2 * u + 1];
      float4 q0 = pq[2 * u], q1 = pq[2 * u + 1];
      const float* w3a = w3 + k0 + skc + 8 * u;
      float4 w30 = *(const float4*)w3a, w31 = *(const float4*)(w3a + 4);
      const float* w1a = w1 + k0 + skc + 8 * u;
      float4 w10 = *(const float4*)w1a, w11 = *(const float4*)(w1a + 4);
      const float* w2a = w2 + k0 + skc + 8 * u;
      float4 w20 = *(const float4*)w2a, w21 = *(const float4*)(w2a + 4);
      v8bf ah;
      ah[0] = (__bf16)(c0.x * w30.x); ah[1] = (__bf16)(c0.y * w30.y);
      ah[2] = (__bf16)(c0.z * w30.z); ah[3] = (__bf16)(c0.w * w30.w);
      ah[4] = (__bf16)(c1.x * w31.x); ah[5] = (__bf16)(c1.y * w31.y);
      ah[6] = (__bf16)(c1.z * w31.z); ah[7] = (__bf16)(c1.w * w31.w);
      *(v8bf*)&Al[sr * LDA64 + skc + 8 * u] = ah;
      *(v8bf*)&Bl[sr * LDA64 + skc + 8 * u] = cvt8f(q0, q1);
      cdot += c0.x * w10.x + c0.y * w10.y + c0.z * w10.z + c0.w * w10.w
            + c1.x * w11.x + c1.y * w11.y + c1.z * w11.z + c1.w * w11.w;
      qdot += q0.x * w20.x + q0.y * w20.y + q0.z * w20.z + q0.w * w20.w
            + q1.x * w21.x + q1.y * w21.y + q1.z * w21.z + q1.w * w21.w;
    }
    __syncthreads();
    int kn = k0 + 64; if (kn >= DM) kn = 0;
    load(kn);
    FRAG_MMA8S(Al, Bl, LDA64, 0);
    FRAG_MMA8S(Al, Bl, LDA64, 32);
    __syncthreads();
  }
  cdot += __shfl_xor(cdot, 1); cdot += __shfl_xor(cdot, 2);
  qdot += __shfl_xor(qdot, 1); qdot += __shfl_xor(qdot, 2);
  if ((t & 3) == 0) { cwL[sr] = cdot; qwL[sr] = qdot; }
  __syncthreads();
  float* Sb = S + (size_t)b * LC * LQ;
#pragma unroll
  for (int x = 0; x < 4; ++x) {
    const int ml = wm * 64 + x * 16 + quad * 4;
    float cv[4];
#pragma unroll
    for (int r = 0; r < 4; ++r) cv[r] = cwL[ml + r];
#pragma unroll
    for (int y = 0; y < 2; ++y) {
      const int jl = wn * 32 + y * 16 + col;
      const float qv = qwL[jl];
#pragma unroll
      for (int r = 0; r < 4; ++r)
        Sb[(size_t)(i0 + ml + r) * LQ + j0 + jl] = acc[x][y][r] + cv[r] + qv;
    }
  }
}

// ---- fused: row softmax (qmask) -> S1  AND per-64i-chunk column stats ----
__global__ __launch_bounds__(1024) void k_softstat(
    const float* __restrict__ S, const float* __restrict__ qmask,
    const float* __restrict__ cmask, __bf16* __restrict__ S1,
    float2* __restrict__ pstat) {
  __shared__ float2 cst[16][LQ];
  const int b = blockIdx.y, ic = blockIdx.x;
  const int tid = threadIdx.x, wv = tid >> 6, lane = tid & 63;
  const int jb = lane * 8;
  const float* qm  = qmask + b * LQ;
  const float* cm  = cmask + b * LC + ic * 64;
  const float* Sb  = S  + ((size_t)b * LC + ic * 64) * LQ;
  __bf16*      S1b = S1 + ((size_t)b * LC + ic * 64) * LQ;
  float qv[8];
  {
    float4 q0 = *(const float4*)(qm + jb), q1 = *(const float4*)(qm + jb + 4);
    qv[0] = q0.x; qv[1] = q0.y; qv[2] = q0.z; qv[3] = q0.w;
    qv[4] = q1.x; qv[5] = q1.y; qv[6] = q1.z; qv[7] = q1.w;
  }
  float colm[8], cols[8];
#pragma unroll
  for (int e = 0; e < 8; ++e) { colm[e] = -3e38f; cols[e] = 0.f; }
  for (int it = 0; it < 4; ++it) {
    const int r = wv * 4 + it;
    const float cmv = cm[r];
    const float* Srow = Sb + (size_t)r * LQ + jb;
    float4 s0 = *(const float4*)Srow, s1 = *(const float4*)(Srow + 4);
    float sv[8] = {s0.x, s0.y, s0.z, s0.w, s1.x, s1.y, s1.z, s1.w};
    float l1[8];
    float m = -3e38f;
#pragma unroll
    for (int e = 0; e < 8; ++e) {
      l1[e] = qv[e] * sv[e] + (1.f - qv[e]) * NEGINF;
      m = fmaxf(m, l1[e]);
    }
#pragma unroll
    for (int off = 32; off; off >>= 1) m = fmaxf(m, __shfl_xor(m, off, 64));
    float ex[8], s = 0.f;
#pragma unroll
    for (int e = 0; e < 8; ++e) { ex[e] = __expf(l1[e] - m); s += ex[e]; }
#pragma unroll
    for (int off = 32; off; off >>= 1) s += __shfl_xor(s, off, 64);
    const float inv = 1.f / s;
    v8bf h;
#pragma unroll
    for (int e = 0; e < 8; ++e) h[e] = (__bf16)(ex[e] * inv);
    *(v8bf*)(S1b + (size_t)r * LQ + jb) = h;
#pragma unroll
    for (int e = 0; e < 8; ++e) {
      float l2 = cmv * sv[e] + (1.f - cmv) * NEGINF;
      if (l2 > colm[e]) { cols[e] *= __expf(colm[e] - l2); colm[e] = l2; }
      cols[e] += __expf(l2 - colm[e]);
    }
  }
#pragma unroll
  for (int e = 0; e < 8; ++e) cst[wv][jb + e] = make_float2(colm[e], cols[e]);
  __syncthreads();
  if (tid < LQ) {
    float M = -3e38f, Sd = 0.f;
#pragma unroll
    for (int k = 0; k < 16; ++k) {
      float2 p = cst[k][tid];
      float nM = fmaxf(M, p.x);
      Sd = Sd * __expf(M - nM) + p.y * __expf(p.x - nM);
      M = nM;
    }
    pstat[((size_t)(b * 16 + ic) * LQ) + tid] = make_float2(M, Sd);
  }
}

// ---- col softmax phase 2: combine stats, write TRANSPOSED S2T[j][i] ----
__global__ void k_colwrite(const float* __restrict__ S, const float* __restrict__ cmask,
                           const float2* __restrict__ pstat, __bf16* __restrict__ S2T) {
  __shared__ float Mf[64], If[64];
  __shared__ __bf16 tile[64][66];
  const int b = blockIdx.z, ic = blockIdx.y, j0 = blockIdx.x * 64;
  if (threadIdx.x < 64) {
    float M = -3e38f, Sd = 0.f;
#pragma unroll
    for (int k = 0; k < 16; ++k) {
      float2 p = pstat[((size_t)(b * 16 + k) * LQ) + j0 + threadIdx.x];
      float nM = fmaxf(M, p.x);
      Sd = Sd * __expf(M - nM) + p.y * __expf(p.x - nM);
      M = nM;
    }
    Mf[threadIdx.x] = M; If[threadIdx.x] = 1.f / Sd;
  }
  __syncthreads();
  const float* Sb = S + ((size_t)b * LC + ic * 64) * LQ;
  const float* cm = cmask + b * LC + ic * 64;
  const int rr = threadIdx.x >> 4, c4 = (threadIdx.x & 15) * 4;
#pragma unroll
  for (int p = 0; p < 4; ++p) {
    const int r = rr + p * 16;
    const float mk = cm[r];
    float4 sv = *(const float4*)(Sb + (size_t)r * LQ + j0 + c4);
    float s[4] = {sv.x, sv.y, sv.z, sv.w};
#pragma unroll
    for (int e = 0; e < 4; ++e) {
      float logit = mk * s[e] + (1.f - mk) * NEGINF;
      tile[r][c4 + e] = (__bf16)(__expf(logit - Mf[c4 + e]) * If[c4 + e]);
    }
  }
  __syncthreads();
  // write: thread -> S2T row jj, 16 consecutive i (32B contiguous x2)
  __bf16* S2Tb = S2T + ((size_t)b * LQ + j0) * LC + ic * 64;
  const int jj = threadIdx.x >> 2, i16 = (threadIdx.x & 3) * 16;
  v8bf h0, h1;
#pragma unroll
  for (int e = 0; e < 8; ++e) { h0[e] = tile[i16 + e][jj]; h1[e] = tile[i16 + 8 + e][jj]; }
  *(v8bf*)(S2Tb + (size_t)jj * LC + i16) = h0;
  *(v8bf*)(S2Tb + (size_t)jj * LC + i16 + 8) = h1;
}

// ---------------- G2: A = S1 @ Q  (8-wave, BK=64, prefetch) ----------------
__global__ __launch_bounds__(512) void k_mfma_A(
    const __bf16* __restrict__ S1, const __bf16* __restrict__ QT, __bf16* __restrict__ Aw) {
  __shared__ __bf16 Al[128 * LDA64], Bl[128 * LDA64];
  int bx = blockIdx.x, by = blockIdx.y, bz = blockIdx.z;
  xcd_remap(bx, by, bz);
  const int b = bz, i0 = by * 128, n0 = bx * 128;
  TILE_SETUP8
  const int sr = t >> 2, skc = (t & 3) * 16;
  const __bf16* Ar = S1 + (size_t)b * LC * LQ + (size_t)(i0 + sr) * LQ + skc;
  const __bf16* Br = QT + (size_t)b * DM * LQ + (size_t)(n0 + sr) * LQ + skc;
  v8bf pa0, pa1, pb0, pb1;
  auto load = [&](int k0) {
    pa0 = *(const v8bf*)(Ar + k0); pa1 = *(const v8bf*)(Ar + k0 + 8);
    pb0 = *(const v8bf*)(Br + k0); pb1 = *(const v8bf*)(Br + k0 + 8);
  };
  load(0);
  ZERO_ACC8
  for (int k0 = 0; k0 < LQ; k0 += 64) {
    *(v8bf*)&Al[sr * LDA64 + skc] = pa0; *(v8bf*)&Al[sr * LDA64 + skc + 8] = pa1;
    *(v8bf*)&Bl[sr * LDA64 + skc] = pb0; *(v8bf*)&Bl[sr * LDA64 + skc + 8] = pb1;
    __syncthreads();
    int kn = k0 + 64; if (kn >= LQ) kn = 0;
    load(kn);
    FRAG_MMA8S(Al, Bl, LDA64, 0);
    FRAG_MMA8S(Al, Bl, LDA64, 32);
    __syncthreads();
  }
  __bf16* Ab = Aw + (size_t)b * LC * DM;
#pragma unroll
  for (int x = 0; x < 4; ++x) {
    const int mB = i0 + wm * 64 + x * 16 + quad * 4;
#pragma unroll
    for (int y = 0; y < 2; ++y) {
      const int n = n0 + wn * 32 + y * 16 + col;
#pragma unroll
      for (int r = 0; r < 4; ++r)
        Ab[(size_t)(mB + r) * DM + n] = (__bf16)acc[x][y][r];
    }
  }
}

// ------- G3: S2TC^T[n][j]  (8-wave, K=Lc, BK=64, prefetch) ----
__global__ __launch_bounds__(512) void k_mfma_T(
    const __bf16* __restrict__ S2T, const __bf16* __restrict__ CT, __bf16* __restrict__ S2TCT) {
  __shared__ __bf16 Al[128 * LDA64], Bl[128 * LDA64];
  int bx = blockIdx.x, by = blockIdx.y, bz = blockIdx.z;
  xcd_remap(bx, by, bz);
  const int b = bz, j0 = by * 128, n0 = bx * 128;
  TILE_SETUP8
  const int sr = t >> 2, skc = (t & 3) * 16;
  const __bf16* Ar = S2T + (size_t)b * LQ * LC + (size_t)(j0 + sr) * LC + skc;
  const __bf16* Br = CT  + (size_t)b * DM * LC + (size_t)(n0 + sr) * LC + skc;
  v8bf pa0, pa1, pb0, pb1;
  auto load = [&](int k0) {
    pa0 = *(const v8bf*)(Ar + k0); pa1 = *(const v8bf*)(Ar + k0 + 8);
    pb0 = *(const v8bf*)(Br + k0); pb1 = *(const v8bf*)(Br + k0 + 8);
  };
  load(0);
  ZERO_ACC8
  for (int k0 = 0; k0 < LC; k0 += 64) {
    *(v8bf*)&Al[sr * LDA64 + skc] = pa0; *(v8bf*)&Al[sr * LDA64 + skc + 8] = pa1;
    *(v8bf*)&Bl[sr * LDA64 + skc] = pb0; *(v8bf*)&Bl[sr * LDA64 + skc + 8] = pb1;
    __syncthreads();
    int kn = k0 + 64; if (kn >= LC) kn = 0;
    load(kn);
    FRAG_MMA8S(Al, Bl, LDA64, 0);
    FRAG_MMA8S(Al, Bl, LDA64, 32);
    __syncthreads();
  }
#pragma unroll
  for (int x = 0; x < 4; ++x) {
    const int jB = j0 + wm * 64 + x * 16 + quad * 4;
#pragma unroll
    for (int y = 0; y < 2; ++y) {
      const int n = n0 + wn * 32 + y * 16 + col;
      v4bf h;
#pragma unroll
      for (int r = 0; r < 4; ++r) h[r] = (__bf16)acc[x][y][r];
      *(v4bf*)&S2TCT[((size_t)b * DM + n) * LQ + jB] = h;
    }
  }
}

// ---------------- G4: Bm = S1 @ S2TC  (8-wave, BK=64, prefetch) --------------
__global__ __launch_bounds__(512) void k_mfma_Bm(
    const __bf16* __restrict__ S1, const __bf16* __restrict__ S2TCT, __bf16* __restrict__ Bmw) {
  __shared__ __bf16 Al[128 * LDA64], Bl[128 * LDA64];
  int bx = blockIdx.x, by = blockIdx.y, bz = blockIdx.z;
  xcd_remap(bx, by, bz);
  const int b = bz, i0 = by * 128, n0 = bx * 128;
  TILE_SETUP8
  const int sr = t >> 2, skc = (t & 3) * 16;
  const __bf16* Ar = S1    + (size_t)b * LC * LQ + (size_t)(i0 + sr) * LQ + skc;
  const __bf16* Br = S2TCT + (size_t)b * DM * LQ + (size_t)(n0 + sr) * LQ + skc;
  v8bf pa0, pa1, pb0, pb1;
  auto load = [&](int k0) {
    pa0 = *(const v8bf*)(Ar + k0); pa1 = *(const v8bf*)(Ar + k0 + 8);
    pb0 = *(const v8bf*)(Br + k0); pb1 = *(const v8bf*)(Br + k0 + 8);
  };
  load(0);
  ZERO_ACC8
  for (int k0 = 0; k0 < LQ; k0 += 64) {
    *(v8bf*)&Al[sr * LDA64 + skc] = pa0; *(v8bf*)&Al[sr * LDA64 + skc + 8] = pa1;
    *(v8bf*)&Bl[sr * LDA64 + skc] = pb0; *(v8bf*)&Bl[sr * LDA64 + skc + 8] = pb1;
    __syncthreads();
    int kn = k0 + 64; if (kn >= LQ) kn = 0;
    load(kn);
    FRAG_MMA8S(Al, Bl, LDA64, 0);
    FRAG_MMA8S(Al, Bl, LDA64, 32);
    __syncthreads();
  }
  __bf16* Bb = Bmw + (size_t)b * LC * DM;
#pragma unroll
  for (int x = 0; x < 4; ++x) {
    const int mB = i0 + wm * 64 + x * 16 + quad * 4;
#pragma unroll
    for (int y = 0; y < 2; ++y) {
      const int n = n0 + wn * 32 + y * 16 + col;
#pragma unroll
      for (int r = 0; r < 4; ++r)
        Bb[(size_t)(mB + r) * DM + n] = (__bf16)acc[x][y][r];
    }
  }
}

// -- G5: out = [C, A, C*A, C*Bm] @ out_w^T + out_b  (A via LDS 4-seg; B via
//    fragment-order global loads from L2-resident Wf — no B LDS at all) ------
__global__ __launch_bounds__(512) void k_mfma_out(
    const float* __restrict__ C, const __bf16* __restrict__ Aw, const __bf16* __restrict__ Bmw,
    const __bf16* __restrict__ Wf, const float* __restrict__ ob, float* __restrict__ out) {
  __shared__ __bf16 Asg[4][128 * LDA32];   // 40 KiB
  int bx = blockIdx.x, by = blockIdx.y, bz = blockIdx.z;
  xcd_remap(bx, by, bz);
  const int b = bz, i0 = by * 128, n0 = bx * 128;
  TILE_SETUP8
  const int sr = t >> 2, skc = (t & 3) * 8;
  const float*  Cr = C   + (size_t)b * LC * DM + (size_t)(i0 + sr) * DM + skc;
  const __bf16* Ar = Aw  + (size_t)b * LC * DM + (size_t)(i0 + sr) * DM + skc;
  const __bf16* Br = Bmw + (size_t)b * LC * DM + (size_t)(i0 + sr) * DM + skc;
  const int ntb = n0 >> 4;
  float4 pc0, pc1; v8bf pA, pB;
  auto load = [&](int kl) {
    pc0 = *(const float4*)(Cr + kl); pc1 = *(const float4*)(Cr + kl + 4);
    pA = *(const v8bf*)(Ar + kl);
    pB = *(const v8bf*)(Br + kl);
  };
  load(0);
  ZERO_ACC8
  for (int kl = 0; kl < DM; kl += 32) {
    float cf[8] = {pc0.x, pc0.y, pc0.z, pc0.w, pc1.x, pc1.y, pc1.z, pc1.w};
    v8bf hC, hCA, hCB;
#pragma unroll
    for (int e = 0; e < 8; ++e) {
      hC[e]  = (__bf16)cf[e];
      hCA[e] = (__bf16)(cf[e] * (float)pA[e]);
      hCB[e] = (__bf16)(cf[e] * (float)pB[e]);
    }
    const int off = sr * LDA32 + skc;
    *(v8bf*)&Asg[0][off] = hC;
    *(v8bf*)&Asg[1][off] = pA;
    *(v8bf*)&Asg[2][off] = hCA;
    *(v8bf*)&Asg[3][off] = hCB;
    __syncthreads();
    int kn = kl + 32; if (kn >= DM) kn = 0;
    load(kn);                                 // prefetch next A-side chunk
    // B-frags for this k-chunk: coalesced 1KB/wave loads, L2-resident
    const int kcb = kl >> 5;
    v8bf bfr[4][2];
#pragma unroll
    for (int s = 0; s < 4; ++s)
#pragma unroll
      for (int y = 0; y < 2; ++y)
        bfr[s][y] = *(const v8bf*)(Wf +
          (size_t)((ntb + wn * 2 + y) * 64 + s * 16 + kcb) * 512 + lane * 8);
#pragma unroll
    for (int s = 0; s < 4; ++s) {
      v8bf af_[4];
#pragma unroll
      for (int x = 0; x < 4; ++x)
        af_[x] = *(const v8bf*)&Asg[s][(wm * 64 + x * 16 + col) * LDA32 + quad * 8];
#pragma unroll
      for (int x = 0; x < 4; ++x) {
        acc[x][0] = MFMA16(af_[x], bfr[s][0], acc[x][0], 0, 0, 0);
        acc[x][1] = MFMA16(af_[x], bfr[s][1], acc[x][1], 0, 0, 0);
      }
    }
    __syncthreads();
  }
  float* outb = out + (size_t)b * LC * DM;
#pragma unroll
  for (int x = 0; x < 4; ++x) {
    const int mB = i0 + wm * 64 + x * 16 + quad * 4;
#pragma unroll
    for (int y = 0; y < 2; ++y) {
      const int n = n0 + wn * 32 + y * 16 + col;
      const float bv = ob[n];
#pragma unroll
      for (int r = 0; r < 4; ++r)
        outb[(size_t)(mB + r) * DM + n] = acc[x][y][r] + bv;
    }
  }
}

extern "C" void kernel_launch(void* const* d_in, const int* in_sizes, int n_in,
                              void* d_out, int out_size, void* d_ws, size_t ws_size,
                              hipStream_t stream) {
  const float* C     = (const float*)d_in[0];
  const float* Q     = (const float*)d_in[1];
  const float* cmask = (const float*)d_in[2];
  const float* qmask = (const float*)d_in[3];
  const float* w     = (const float*)d_in[4];
  const float* out_w = (const float*)d_in[5];
  const float* out_b = (const float*)d_in[6];
  float* out = (float*)d_out;

  // ---- workspace carve (72 MiB + 128 KiB; validated). Aliased by lifetime:
  //  R[0,16Mi):   S.lo          -> Aw
  //  R[16,32Mi):  S.hi          -> CT -> Bmw
  //  +32Mi: S1 (16 Mi)
  //  +48Mi: S2T (16 Mi)        -> OWfrag (2 Mi, after k_mfma_T)
  //  +64Mi: pstat(1Mi) -> QT(8Mi) -> S2TCT(8Mi)
  char* base = (char*)d_ws;
  char*   R      = base + 131072;
  float*  S      = (float*)R;
  __bf16* Aw     = (__bf16*)R;
  __bf16* CT     = (__bf16*)(R + (16u << 20));
  __bf16* Bmw    = (__bf16*)(R + (16u << 20));
  __bf16* S1     = (__bf16*)(base + 131072 + (32u << 20));
  __bf16* S2T    = (__bf16*)(base + 131072 + (48u << 20));
  __bf16* OWfrag = S2T;   // 2 MiB, written after k_mfma_T consumes S2T
  char*   Z      = base + 131072 + (64u << 20);
  float2* pstat  = (float2*)Z;
  __bf16* QT     = (__bf16*)Z;
  __bf16* S2TCT  = (__bf16*)Z;
  (void)in_sizes; (void)n_in; (void)out_size; (void)ws_size;

  k_mfma_S<<<dim3(LQ / 128, LC / 128, NB), 512, 0, stream>>>(C, Q, w, S);
  k_softstat<<<dim3(LC / 64, NB), 1024, 0, stream>>>(S, qmask, cmask, S1, pstat);
  k_colwrite<<<dim3(LQ / 64, LC / 64, NB), 256, 0, stream>>>(S, cmask, pstat, S2T);
  k_transpose<<<dim3(DM / 64, LQ / 64, NB), 256, 0, stream>>>(Q, QT, LQ, DM);
  k_transpose<<<dim3(DM / 64, LC / 64, NB), 256, 0, stream>>>(C, CT, LC, DM);
  k_mfma_A<<<dim3(DM / 128, LC / 128, NB), 512, 0, stream>>>(S1, QT, Aw);
  k_mfma_T<<<dim3(DM / 128, LQ / 128, NB), 512, 0, stream>>>(S2T, CT, S2TCT);
  k_owfrag<<<512, 256, 0, stream>>>(out_w, OWfrag);
  k_mfma_Bm<<<dim3(DM / 128, LC / 128, NB), 512, 0, stream>>>(S1, S2TCT, Bmw);
  k_mfma_out<<<dim3(DM / 128, LC / 128, NB), 512, 0, stream>>>(C, Aw, Bmw, OWfrag, out_b, out);
}